// Round 1
// baseline (137124.817 us; speedup 1.0000x reference)
//
#include <hip/hip_runtime.h>

#define T_ 512
#define B_ 64
#define D_ 1024
#define A_ 128
#define KCAT_ 2304   // 2176 (wih) + 128 (whh)
#define PSZ_ 14336
#define NBLK 256

typedef __attribute__((ext_vector_type(8))) short short8;
typedef __attribute__((ext_vector_type(4))) short short4_t;
typedef __attribute__((ext_vector_type(4))) float float4_t;

__device__ __forceinline__ float sigf(float x){ return 1.0f/(1.0f + __expf(-x)); }
__device__ __forceinline__ float tanhf_(float x){ return 2.0f/(1.0f + __expf(-2.0f*x)) - 1.0f; }

__device__ __forceinline__ short f2bf(float f){
  unsigned u = __builtin_bit_cast(unsigned, f);
  u += 0x7fffu + ((u >> 16) & 1u);           // RNE
  return (short)(u >> 16);
}
__device__ __forceinline__ float bf2f(short s){
  unsigned u = ((unsigned)(unsigned short)s) << 16;
  return __builtin_bit_cast(float, u);
}

// ---------- prep kernels (once per launch) ----------
__global__ __launch_bounds__(256) void pk_cat(const float* __restrict__ wih,
                                              const float* __restrict__ whh,
                                              short* __restrict__ dst){
  int c = blockIdx.x*256 + threadIdx.x;     // 0..2303
  int n = blockIdx.y;                       // 0..511
  if (c >= KCAT_) return;
  float v = (c < 2176) ? wih[(size_t)n*2176 + c] : whh[n*A_ + (c - 2176)];
  dst[(size_t)n*KCAT_ + c] = f2bf(v);
}
__global__ __launch_bounds__(256) void pk_conv(const float* __restrict__ src,
                                               short* __restrict__ dst, int n){
  int i = blockIdx.x*256 + threadIdx.x;
  if (i < n) dst[i] = f2bf(src[i]);
}

// ---------- persistent fused kernel ----------
struct Args {
  const float* x;
  const short* Wcat0; const short* Wcat1;
  const float* bih0;  const float* bih1;
  const float* bhh0;  const float* bhh1;
  const short* pw0;   const short* pw1;
  const float* pb0;   const float* pb1;
  const short* fwi0;  const short* fwi1;
  const short* fwh0;  const short* fwh1;
  const float* fb0;   const float* fb1;
  float* gates; float* ac; float* fc; float* polp;
  short* xp0; short* hp1; short* fhbf; short* ahbf;
  float* out;
  unsigned* bar;
};

// device-wide barrier: monotonic counter, agent-scope fences for cross-XCD
// visibility (release: wb L2 dirty lines to LLC; acquire: inv L1/L2).
__device__ __forceinline__ void gsync(unsigned* bar, unsigned target){
  __syncthreads();
  if (threadIdx.x == 0){
    __threadfence();
    __hip_atomic_fetch_add(bar, 1u, __ATOMIC_RELAXED, __HIP_MEMORY_SCOPE_AGENT);
    while (__hip_atomic_load(bar, __ATOMIC_RELAXED, __HIP_MEMORY_SCOPE_AGENT) < target)
      __builtin_amdgcn_s_sleep(2);
    __threadfence();
  }
  __syncthreads();
}

__global__ __launch_bounds__(256, 1) void fused(Args P){
  const int tid  = threadIdx.x;
  const int blk  = blockIdx.x;
  const int wq   = tid >> 6;
  const int lane = tid & 63;
  const int row  = lane & 15, quad = lane >> 4;

  __shared__ float red[4][256];     // S1 cross-wave K-split reduction
  __shared__ short ah_s[64*136];    // S2 redundant a-cell output

  unsigned ph = 0;

  for (int t = 0; t < T_; ++t){
    const int par = t & 1, cur = par ^ 1;
    const float* xt = P.x + (size_t)t*B_*D_;
    #pragma unroll
    for (int l = 0; l < 2; ++l){
      const short* Wcat = l ? P.Wcat1 : P.Wcat0;
      const float* bih  = l ? P.bih1  : P.bih0;
      const float* bhh  = l ? P.bhh1  : P.bhh0;
      const short* pw   = l ? P.pw1   : P.pw0;
      const float* pb   = l ? P.pb1   : P.pb0;
      const short* fwi  = l ? P.fwi1  : P.fwi0;
      const short* fwh  = l ? P.fwh1  : P.fwh0;
      const float* fb   = l ? P.fb1   : P.fb0;
      short* fh_l = P.fhbf + (size_t)l*B_*D_;
      const short* ahp = l ? (P.ahbf + (0*2 + cur)*B_*A_)   // ah[0] this step
                           : (P.ahbf + (1*2 + par)*B_*A_);  // ah[1] prev step
      const short* ahs = P.ahbf + (l*2 + par)*B_*A_;
      short* ah_out    = P.ahbf + (l*2 + cur)*B_*A_;
      const float* ac_old = P.ac + (l*2 + par)*A_*B_;
      float* ac_new       = P.ac + (l*2 + cur)*A_*B_;
      float* fc_l = P.fc + (size_t)l*B_*D_;

      // ============ S1: a-gates GEMM [512x64, K=2304], K split over 4 waves ============
      if (blk < 128){
        const int m0  = (blk >> 2) * 16;
        const int nt1 = blk & 3;
        const int bq  = nt1*16 + row;
        const short* wrow = Wcat + (size_t)(m0 + row)*KCAT_ + quad*8;
        float4_t acc = {0.f,0.f,0.f,0.f};
        if (l == 0){
          const float* xp = xt + (size_t)bq*D_ + quad*8;
          #pragma unroll
          for (int i = 0; i < 8; ++i){
            const int ks = wq + 4*i;
            short8 a = *(const short8*)(wrow + ks*32);
            float4_t x0 = *(const float4_t*)(xp + ks*32);
            float4_t x1 = *(const float4_t*)(xp + ks*32 + 4);
            short8 bfr;
            #pragma unroll
            for (int r = 0; r < 4; ++r){ bfr[r] = f2bf(x0[r]); bfr[4+r] = f2bf(x1[r]); }
            acc = __builtin_amdgcn_mfma_f32_16x16x32_bf16(a, bfr, acc, 0, 0, 0);
          }
        } else {
          const short* xp = P.fhbf + (size_t)bq*D_ + quad*8;  // layer0 fh (this step)
          #pragma unroll
          for (int i = 0; i < 8; ++i){
            const int ks = wq + 4*i;
            short8 a = *(const short8*)(wrow + ks*32);
            short8 bfr = *(const short8*)(xp + ks*32);
            acc = __builtin_amdgcn_mfma_f32_16x16x32_bf16(a, bfr, acc, 0, 0, 0);
          }
        }
        {
          const short* hp = fh_l + (size_t)bq*D_ + quad*8;
          #pragma unroll
          for (int i = 0; i < 8; ++i){
            const int ks = wq + 4*i;
            short8 a = *(const short8*)(wrow + 1024 + ks*32);
            short8 bfr = *(const short8*)(hp + ks*32);
            acc = __builtin_amdgcn_mfma_f32_16x16x32_bf16(a, bfr, acc, 0, 0, 0);
          }
        }
        {
          short8 a = *(const short8*)(wrow + 2048 + wq*32);
          short8 bfr = *(const short8*)(ahp + bq*A_ + quad*8 + wq*32);
          acc = __builtin_amdgcn_mfma_f32_16x16x32_bf16(a, bfr, acc, 0, 0, 0);
        }
        {
          short8 a = *(const short8*)(wrow + 2176 + wq*32);
          short8 bfr = *(const short8*)(ahs + bq*A_ + quad*8 + wq*32);
          acc = __builtin_amdgcn_mfma_f32_16x16x32_bf16(a, bfr, acc, 0, 0, 0);
        }
        #pragma unroll
        for (int r = 0; r < 4; ++r) red[wq][(r << 6) | lane] = acc[r];
        __syncthreads();
        {
          float s = red[0][tid] + red[1][tid] + red[2][tid] + red[3][tid];
          const int rr = tid >> 6, ll = tid & 63;
          const int n = m0 + ((ll >> 4) << 2) + rr;
          const int b = nt1*16 + (ll & 15);
          P.gates[n*B_ + b] = s + bih[n] + bhh[n];
        }
      }
      gsync(P.bar, ++ph * NBLK);

      // ============ S2: a-cell (redundant per block) + pol GEMM ============
      if (blk < 224){
        const int b = tid & 63, q = tid >> 6;
        #pragma unroll 4
        for (int jj = 0; jj < 32; ++jj){
          const int j = q*32 + jj;
          float gi = P.gates[(j      )*B_ + b];
          float gf = P.gates[(j + 128)*B_ + b];
          float gg = P.gates[(j + 256)*B_ + b];
          float go = P.gates[(j + 384)*B_ + b];
          float c  = ac_old[j*B_ + b];
          float c2 = sigf(gf)*c + sigf(gi)*tanhf_(gg);
          float h2 = sigf(go)*tanhf_(c2);
          ah_s[b*136 + j] = f2bf(h2);
          if (blk == 0){
            ac_new[j*B_ + b] = c2;
            ah_out[b*A_ + j] = f2bf(h2);
          }
        }
        __syncthreads();
        const int m0 = (blk*4 + wq)*16;
        const short* wrow = pw + (size_t)(m0 + row)*A_ + quad*8;
        float4_t acc[4] = {{0.f,0.f,0.f,0.f},{0.f,0.f,0.f,0.f},{0.f,0.f,0.f,0.f},{0.f,0.f,0.f,0.f}};
        #pragma unroll
        for (int ks = 0; ks < 4; ++ks){
          short8 a = *(const short8*)(wrow + ks*32);
          #pragma unroll
          for (int nt = 0; nt < 4; ++nt){
            short8 bf8 = *(const short8*)&ah_s[(nt*16 + row)*136 + ks*32 + quad*8];
            acc[nt] = __builtin_amdgcn_mfma_f32_16x16x32_bf16(a, bf8, acc[nt], 0, 0, 0);
          }
        }
        const int c0 = m0 + quad*4;
        float4_t pbv = *(const float4_t*)(pb + c0);
        if (m0 < 1024){
          #pragma unroll
          for (int nt = 0; nt < 4; ++nt){
            const int b2 = nt*16 + row;
            float4_t xv;
            if (l == 0){ xv = *(const float4_t*)(xt + (size_t)b2*D_ + c0); }
            else {
              short4_t xb = *(const short4_t*)(P.fhbf + (size_t)b2*D_ + c0);
              #pragma unroll
              for (int r = 0; r < 4; ++r) xv[r] = bf2f(xb[r]);
            }
            short4_t o;
            #pragma unroll
            for (int r = 0; r < 4; ++r) o[r] = f2bf((acc[nt][r] + pbv[r]) * xv[r]);
            *(short4_t*)(P.xp0 + (size_t)b2*D_ + c0) = o;
          }
        } else if (m0 < 2048){
          const int cc = c0 - 1024;
          #pragma unroll
          for (int nt = 0; nt < 4; ++nt){
            const int b2 = nt*16 + row;
            short4_t hb = *(const short4_t*)(fh_l + (size_t)b2*D_ + cc);
            short4_t o;
            #pragma unroll
            for (int r = 0; r < 4; ++r) o[r] = f2bf((acc[nt][r] + pbv[r]) * bf2f(hb[r]));
            *(short4_t*)(P.hp1 + (size_t)b2*D_ + cc) = o;
          }
        } else {
          const int cc = c0 - 2048;
          #pragma unroll
          for (int nt = 0; nt < 4; ++nt){
            const int b2 = nt*16 + row;
            float4_t vv;
            #pragma unroll
            for (int r = 0; r < 4; ++r) vv[r] = acc[nt][r] + pbv[r];
            *(float4_t*)(P.polp + (size_t)b2*12288 + cc) = vv;
          }
        }
      }
      gsync(P.bar, ++ph * NBLK);

      // ============ S3: f-gates (two K=1024 GEMMs) + f-cell ============
      if (blk < 64){
        const int nt3 = wq;
        const int j0 = blk*16;
        const short* wIr[4]; const short* wHr[4];
        #pragma unroll
        for (int g = 0; g < 4; ++g){
          wIr[g] = fwi + (size_t)(g*D_ + j0 + row)*D_ + quad*8;
          wHr[g] = fwh + (size_t)(g*D_ + j0 + row)*D_ + quad*8;
        }
        const short* bx = P.xp0 + (size_t)(nt3*16 + row)*D_ + quad*8;
        const short* bh = P.hp1 + (size_t)(nt3*16 + row)*D_ + quad*8;
        float4_t aI[4] = {{0.f,0.f,0.f,0.f},{0.f,0.f,0.f,0.f},{0.f,0.f,0.f,0.f},{0.f,0.f,0.f,0.f}};
        float4_t aH[4] = {{0.f,0.f,0.f,0.f},{0.f,0.f,0.f,0.f},{0.f,0.f,0.f,0.f},{0.f,0.f,0.f,0.f}};
        #pragma unroll 2
        for (int ks = 0; ks < 32; ++ks){
          const int kg = ks*32;
          short8 bxf = *(const short8*)(bx + kg);
          short8 bhf = *(const short8*)(bh + kg);
          #pragma unroll
          for (int g = 0; g < 4; ++g){
            short8 ai  = *(const short8*)(wIr[g] + kg);
            short8 ah8 = *(const short8*)(wHr[g] + kg);
            aI[g] = __builtin_amdgcn_mfma_f32_16x16x32_bf16(ai,  bxf, aI[g], 0, 0, 0);
            aH[g] = __builtin_amdgcn_mfma_f32_16x16x32_bf16(ah8, bhf, aH[g], 0, 0, 0);
          }
        }
        const int b3 = nt3*16 + row;
        const int jr = j0 + quad*4;
        float4_t gl[4];
        #pragma unroll
        for (int g = 0; g < 4; ++g){
          const float* pbase = P.polp + (size_t)b3*12288 + g*D_ + jr;
          float4_t p2 = *(const float4_t*)(pbase);
          float4_t p3 = *(const float4_t*)(pbase + 4096);
          float4_t p4 = *(const float4_t*)(pbase + 8192);
          float4_t fbv = *(const float4_t*)(fb + g*D_ + jr);
          #pragma unroll
          for (int r = 0; r < 4; ++r)
            gl[g][r] = aI[g][r]*p2[r] + fbv[r]*p4[r] + aH[g][r]*p3[r];
        }
        float4_t cold = *(const float4_t*)(fc_l + (size_t)b3*D_ + jr);
        float4_t cnew, hnew;
        #pragma unroll
        for (int r = 0; r < 4; ++r){
          float c2 = sigf(gl[1][r])*cold[r] + sigf(gl[0][r])*tanhf_(gl[2][r]);
          float h2 = sigf(gl[3][r])*tanhf_(c2);
          cnew[r] = c2; hnew[r] = h2;
        }
        *(float4_t*)(fc_l + (size_t)b3*D_ + jr) = cnew;
        short4_t hb;
        #pragma unroll
        for (int r = 0; r < 4; ++r) hb[r] = f2bf(hnew[r]);
        *(short4_t*)(fh_l + (size_t)b3*D_ + jr) = hb;
        if (l == 1)
          *(float4_t*)(P.out + (size_t)t*B_*D_ + (size_t)b3*D_ + jr) = hnew;
      }
      gsync(P.bar, ++ph * NBLK);
    }
  }
}

extern "C" void kernel_launch(void* const* d_in, const int* in_sizes, int n_in,
                              void* d_out, int out_size, void* d_ws, size_t ws_size,
                              hipStream_t stream) {
  const float* x = (const float*)d_in[0];
  const float* a_wih[2] = {(const float*)d_in[1],  (const float*)d_in[10]};
  const float* a_whh[2] = {(const float*)d_in[2],  (const float*)d_in[11]};
  const float* a_bih[2] = {(const float*)d_in[3],  (const float*)d_in[12]};
  const float* a_bhh[2] = {(const float*)d_in[4],  (const float*)d_in[13]};
  const float* p_w[2]   = {(const float*)d_in[5],  (const float*)d_in[14]};
  const float* p_b[2]   = {(const float*)d_in[6],  (const float*)d_in[15]};
  const float* f_wih[2] = {(const float*)d_in[7],  (const float*)d_in[16]};
  const float* f_whh[2] = {(const float*)d_in[8],  (const float*)d_in[17]};
  const float* f_b[2]   = {(const float*)d_in[9],  (const float*)d_in[18]};

  char* w = (char*)d_ws;
  float* gates = (float*)(w + 0);          // 512*64*4        = 131072
  float* ac    = (float*)(w + 131072);     // [l][par][128*64]= 131072
  float* fc    = (float*)(w + 262144);     // [l][64*1024]    = 524288
  float* polp  = (float*)(w + 786432);     // 64*12288*4      = 3145728
  short* xp0   = (short*)(w + 3932160);    // 64*1024*2       = 131072
  short* hp1   = (short*)(w + 4063232);    // 131072
  short* fhbf  = (short*)(w + 4194304);    // [l][64*1024]    = 262144
  short* ahbf  = (short*)(w + 4456448);    // [l][par][64*128]= 65536
  short* Wcat  = (short*)(w + 4521984);    // [l][512*2304]   = 4718592
  short* pwbf  = (short*)(w + 9240576);    // [l][14336*128]  = 7340032
  short* fwihb = (short*)(w + 16580608);   // [l][4096*1024]  = 16777216
  short* fwhhb = (short*)(w + 33357824);   // 16777216 -> end 50135040
  unsigned* bar = (unsigned*)(w + 50135040); // 64 B barrier counter

  // zero recurrent state: ac+fc, fh_bf+ah_bf, barrier counter
  hipMemsetAsync(w + 131072, 0, 655360, stream);
  hipMemsetAsync(w + 4194304, 0, 327680, stream);
  hipMemsetAsync(w + 50135040, 0, 64, stream);

  // weight conversion
  for (int l = 0; l < 2; ++l){
    pk_cat<<<dim3(9,512), 256, 0, stream>>>(a_wih[l], a_whh[l], Wcat + (size_t)l*512*KCAT_);
    pk_conv<<<(PSZ_*A_ + 255)/256, 256, 0, stream>>>(p_w[l], pwbf + (size_t)l*PSZ_*A_, PSZ_*A_);
    pk_conv<<<(4*D_*D_ + 255)/256, 256, 0, stream>>>(f_wih[l], fwihb + (size_t)l*4*D_*D_, 4*D_*D_);
    pk_conv<<<(4*D_*D_ + 255)/256, 256, 0, stream>>>(f_whh[l], fwhhb + (size_t)l*4*D_*D_, 4*D_*D_);
  }

  Args A;
  A.x = x;
  A.Wcat0 = Wcat;  A.Wcat1 = Wcat + (size_t)512*KCAT_;
  A.bih0 = a_bih[0]; A.bih1 = a_bih[1];
  A.bhh0 = a_bhh[0]; A.bhh1 = a_bhh[1];
  A.pw0 = pwbf;    A.pw1 = pwbf + (size_t)PSZ_*A_;
  A.pb0 = p_b[0];  A.pb1 = p_b[1];
  A.fwi0 = fwihb;  A.fwi1 = fwihb + (size_t)4*D_*D_;
  A.fwh0 = fwhhb;  A.fwh1 = fwhhb + (size_t)4*D_*D_;
  A.fb0 = f_b[0];  A.fb1 = f_b[1];
  A.gates = gates; A.ac = ac; A.fc = fc; A.polp = polp;
  A.xp0 = xp0; A.hp1 = hp1; A.fhbf = fhbf; A.ahbf = ahbf;
  A.out = (float*)d_out;
  A.bar = bar;

  fused<<<NBLK, 256, 0, stream>>>(A);
}

// Round 2
// 96723.865 us; speedup vs baseline: 1.4177x; 1.4177x over previous
//
#include <hip/hip_runtime.h>

#define T_ 512
#define B_ 64
#define D_ 1024
#define A_ 128
#define KCAT_ 2304   // 2176 (wih) + 128 (whh)
#define PSZ_ 14336
#define NBLK 224

typedef __attribute__((ext_vector_type(8))) short short8;
typedef __attribute__((ext_vector_type(4))) short short4_t;
typedef __attribute__((ext_vector_type(4))) float float4_t;
typedef __attribute__((ext_vector_type(2))) unsigned long long ull2;

__device__ __forceinline__ float sigf(float x){ return 1.0f/(1.0f + __expf(-x)); }
__device__ __forceinline__ float tanhf_(float x){ return 2.0f/(1.0f + __expf(-2.0f*x)) - 1.0f; }

__device__ __forceinline__ short f2bf(float f){
  unsigned u = __builtin_bit_cast(unsigned, f);
  u += 0x7fffu + ((u >> 16) & 1u);           // RNE
  return (short)(u >> 16);
}
__device__ __forceinline__ float bf2f(short s){
  unsigned u = ((unsigned)(unsigned short)s) << 16;
  return __builtin_bit_cast(float, u);
}

// ---- coherent (agent-scope, LLC-backed, no cache-maintenance) accessors ----
// relaxed agent atomics compile to global_load/store with sc0 sc1: bypass the
// non-coherent per-XCD L2, hit the Infinity Cache. No buffer_wbl2/buffer_inv.
__device__ __forceinline__ unsigned ld_u32_cg(const void* p){
  return __hip_atomic_load((const unsigned*)p, __ATOMIC_RELAXED, __HIP_MEMORY_SCOPE_AGENT);
}
__device__ __forceinline__ unsigned long long ld_u64_cg(const void* p){
  return __hip_atomic_load((const unsigned long long*)p, __ATOMIC_RELAXED, __HIP_MEMORY_SCOPE_AGENT);
}
__device__ __forceinline__ void st_u32_cg(void* p, unsigned v){
  __hip_atomic_store((unsigned*)p, v, __ATOMIC_RELAXED, __HIP_MEMORY_SCOPE_AGENT);
}
__device__ __forceinline__ void st_u64_cg(void* p, unsigned long long v){
  __hip_atomic_store((unsigned long long*)p, v, __ATOMIC_RELAXED, __HIP_MEMORY_SCOPE_AGENT);
}
__device__ __forceinline__ float ld_f_cg(const float* p){
  unsigned u = ld_u32_cg(p); return __builtin_bit_cast(float, u);
}
__device__ __forceinline__ void st_f_cg(float* p, float v){
  st_u32_cg(p, __builtin_bit_cast(unsigned, v));
}
__device__ __forceinline__ short8 ld_bf8_cg(const short* p){
  ull2 t; t.x = ld_u64_cg(p); t.y = ld_u64_cg(p + 4);
  return __builtin_bit_cast(short8, t);
}
__device__ __forceinline__ short4_t ld_bf4_cg(const short* p){
  return __builtin_bit_cast(short4_t, ld_u64_cg(p));
}
__device__ __forceinline__ float4_t ld_f4_cg(const float* p){
  ull2 t; t.x = ld_u64_cg(p); t.y = ld_u64_cg(p + 2);
  return __builtin_bit_cast(float4_t, t);
}
__device__ __forceinline__ void st_bf4_cg(short* p, short4_t v){
  st_u64_cg(p, __builtin_bit_cast(unsigned long long, v));
}
__device__ __forceinline__ void st_f4_cg(float* p, float4_t v){
  ull2 t = __builtin_bit_cast(ull2, v);
  st_u64_cg(p, t.x); st_u64_cg(p + 2, t.y);
}

// ---------- prep kernels (once per launch) ----------
__global__ __launch_bounds__(256) void pk_cat(const float* __restrict__ wih,
                                              const float* __restrict__ whh,
                                              short* __restrict__ dst){
  int c = blockIdx.x*256 + threadIdx.x;     // 0..2303
  int n = blockIdx.y;                       // 0..511
  if (c >= KCAT_) return;
  float v = (c < 2176) ? wih[(size_t)n*2176 + c] : whh[n*A_ + (c - 2176)];
  dst[(size_t)n*KCAT_ + c] = f2bf(v);
}
__global__ __launch_bounds__(256) void pk_conv(const float* __restrict__ src,
                                               short* __restrict__ dst, int n){
  int i = blockIdx.x*256 + threadIdx.x;
  if (i < n) dst[i] = f2bf(src[i]);
}

// ---------- persistent fused kernel ----------
struct Args {
  const float* x;
  const short* Wcat0; const short* Wcat1;
  const float* bih0;  const float* bih1;
  const float* bhh0;  const float* bhh1;
  const short* pw0;   const short* pw1;
  const float* pb0;   const float* pb1;
  const short* fwi0;  const short* fwi1;
  const short* fwh0;  const short* fwh1;
  const float* fb0;   const float* fb1;
  float* gates; float* ac; float* fc; float* polp;
  short* xp0; short* hp1; short* fhbf; short* ahbf;
  float* out;
  unsigned* bar;
};

// fence-free device barrier: __syncthreads drains each thread's outstanding
// write-through (sc1) stores before s_barrier; relaxed agent atomics on the
// counter are coherent at LLC. No L2 writeback/invalidate anywhere.
__device__ __forceinline__ void gsync(unsigned* bar, unsigned target){
  __syncthreads();
  if (threadIdx.x == 0){
    __hip_atomic_fetch_add(bar, 1u, __ATOMIC_RELAXED, __HIP_MEMORY_SCOPE_AGENT);
    while (__hip_atomic_load(bar, __ATOMIC_RELAXED, __HIP_MEMORY_SCOPE_AGENT) < target)
      __builtin_amdgcn_s_sleep(2);
  }
  __syncthreads();
}

__global__ __launch_bounds__(256, 1) void fused(Args P){
  const int tid  = threadIdx.x;
  const int blk  = blockIdx.x;
  const int wq   = tid >> 6;
  const int lane = tid & 63;
  const int row  = lane & 15, quad = lane >> 4;

  __shared__ float red[4][256];     // S1 cross-wave K-split reduction
  __shared__ short ah_s[64*136];    // S2 redundant a-cell output

  unsigned ph = 0;

  for (int t = 0; t < T_; ++t){
    const int par = t & 1, cur = par ^ 1;
    const float* xt = P.x + (size_t)t*B_*D_;
    #pragma unroll
    for (int l = 0; l < 2; ++l){
      const short* Wcat = l ? P.Wcat1 : P.Wcat0;
      const float* bih  = l ? P.bih1  : P.bih0;
      const float* bhh  = l ? P.bhh1  : P.bhh0;
      const short* pw   = l ? P.pw1   : P.pw0;
      const float* pb   = l ? P.pb1   : P.pb0;
      const short* fwi  = l ? P.fwi1  : P.fwi0;
      const short* fwh  = l ? P.fwh1  : P.fwh0;
      const float* fb   = l ? P.fb1   : P.fb0;
      short* fh_l = P.fhbf + (size_t)l*B_*D_;
      const short* ahp = l ? (P.ahbf + (0*2 + cur)*B_*A_)   // ah[0] this step
                           : (P.ahbf + (1*2 + par)*B_*A_);  // ah[1] prev step
      const short* ahs = P.ahbf + (l*2 + par)*B_*A_;
      short* ah_out    = P.ahbf + (l*2 + cur)*B_*A_;
      const float* ac_old = P.ac + (l*2 + par)*A_*B_;
      float* ac_new       = P.ac + (l*2 + cur)*A_*B_;
      float* fc_l = P.fc + (size_t)l*B_*D_;

      // ============ S1: a-gates GEMM [512x64, K=2304], K split over 4 waves ============
      if (blk < 128){
        const int m0  = (blk >> 2) * 16;
        const int nt1 = blk & 3;
        const int bq  = nt1*16 + row;
        const short* wrow = Wcat + (size_t)(m0 + row)*KCAT_ + quad*8;
        float4_t acc = {0.f,0.f,0.f,0.f};
        if (l == 0){
          const float* xp = xt + (size_t)bq*D_ + quad*8;
          #pragma unroll
          for (int i = 0; i < 8; ++i){
            const int ks = wq + 4*i;
            short8 a = *(const short8*)(wrow + ks*32);
            float4_t x0 = *(const float4_t*)(xp + ks*32);
            float4_t x1 = *(const float4_t*)(xp + ks*32 + 4);
            short8 bfr;
            #pragma unroll
            for (int r = 0; r < 4; ++r){ bfr[r] = f2bf(x0[r]); bfr[4+r] = f2bf(x1[r]); }
            acc = __builtin_amdgcn_mfma_f32_16x16x32_bf16(a, bfr, acc, 0, 0, 0);
          }
        } else {
          const short* xp = P.fhbf + (size_t)bq*D_;          // layer0 fh (this step)
          #pragma unroll
          for (int i = 0; i < 8; ++i){
            const int ks = wq + 4*i;
            short8 a = *(const short8*)(wrow + ks*32);
            short8 bfr = ld_bf8_cg(xp + quad*8 + ks*32);
            acc = __builtin_amdgcn_mfma_f32_16x16x32_bf16(a, bfr, acc, 0, 0, 0);
          }
        }
        {
          const short* hp = fh_l + (size_t)bq*D_;
          #pragma unroll
          for (int i = 0; i < 8; ++i){
            const int ks = wq + 4*i;
            short8 a = *(const short8*)(wrow + 1024 + ks*32);
            short8 bfr = ld_bf8_cg(hp + quad*8 + ks*32);
            acc = __builtin_amdgcn_mfma_f32_16x16x32_bf16(a, bfr, acc, 0, 0, 0);
          }
        }
        {
          short8 a = *(const short8*)(wrow + 2048 + wq*32);
          short8 bfr = ld_bf8_cg(ahp + bq*A_ + quad*8 + wq*32);
          acc = __builtin_amdgcn_mfma_f32_16x16x32_bf16(a, bfr, acc, 0, 0, 0);
        }
        {
          short8 a = *(const short8*)(wrow + 2176 + wq*32);
          short8 bfr = ld_bf8_cg(ahs + bq*A_ + quad*8 + wq*32);
          acc = __builtin_amdgcn_mfma_f32_16x16x32_bf16(a, bfr, acc, 0, 0, 0);
        }
        #pragma unroll
        for (int r = 0; r < 4; ++r) red[wq][(r << 6) | lane] = acc[r];
        __syncthreads();
        {
          float s = red[0][tid] + red[1][tid] + red[2][tid] + red[3][tid];
          const int rr = tid >> 6, ll = tid & 63;
          const int n = m0 + ((ll >> 4) << 2) + rr;
          const int b = nt1*16 + (ll & 15);
          st_f_cg(&P.gates[n*B_ + b], s + bih[n] + bhh[n]);
        }
      }
      gsync(P.bar, ++ph * NBLK);

      // ============ S2: a-cell (redundant per block) + pol GEMM ============
      {
        const int b = tid & 63, q = tid >> 6;
        unsigned long long pk = 0;
        #pragma unroll 8
        for (int jj = 0; jj < 32; ++jj){
          const int j = q*32 + jj;
          float gi = ld_f_cg(&P.gates[(j      )*B_ + b]);
          float gf = ld_f_cg(&P.gates[(j + 128)*B_ + b]);
          float gg = ld_f_cg(&P.gates[(j + 256)*B_ + b]);
          float go = ld_f_cg(&P.gates[(j + 384)*B_ + b]);
          float c  = ld_f_cg(&ac_old[j*B_ + b]);
          float c2 = sigf(gf)*c + sigf(gi)*tanhf_(gg);
          float h2 = sigf(go)*tanhf_(c2);
          short hb = f2bf(h2);
          ah_s[b*136 + j] = hb;
          if (blk == 0){
            st_f_cg(&ac_new[j*B_ + b], c2);
            pk |= (unsigned long long)(unsigned short)hb << ((jj & 3)*16);
            if ((jj & 3) == 3){ st_u64_cg(ah_out + b*A_ + (j - 3), pk); pk = 0; }
          }
        }
        __syncthreads();
        const int m0 = (blk*4 + wq)*16;
        const short* wrow = pw + (size_t)(m0 + row)*A_ + quad*8;
        float4_t acc[4] = {{0.f,0.f,0.f,0.f},{0.f,0.f,0.f,0.f},{0.f,0.f,0.f,0.f},{0.f,0.f,0.f,0.f}};
        #pragma unroll
        for (int ks = 0; ks < 4; ++ks){
          short8 a = *(const short8*)(wrow + ks*32);
          #pragma unroll
          for (int nt = 0; nt < 4; ++nt){
            short8 bf8 = *(const short8*)&ah_s[(nt*16 + row)*136 + ks*32 + quad*8];
            acc[nt] = __builtin_amdgcn_mfma_f32_16x16x32_bf16(a, bf8, acc[nt], 0, 0, 0);
          }
        }
        const int c0 = m0 + quad*4;
        float4_t pbv = *(const float4_t*)(pb + c0);
        if (m0 < 1024){
          #pragma unroll
          for (int nt = 0; nt < 4; ++nt){
            const int b2 = nt*16 + row;
            float4_t xv;
            if (l == 0){ xv = *(const float4_t*)(xt + (size_t)b2*D_ + c0); }
            else {
              short4_t xb = ld_bf4_cg(P.fhbf + (size_t)b2*D_ + c0);
              #pragma unroll
              for (int r = 0; r < 4; ++r) xv[r] = bf2f(xb[r]);
            }
            short4_t o;
            #pragma unroll
            for (int r = 0; r < 4; ++r) o[r] = f2bf((acc[nt][r] + pbv[r]) * xv[r]);
            st_bf4_cg(P.xp0 + (size_t)b2*D_ + c0, o);
          }
        } else if (m0 < 2048){
          const int cc = c0 - 1024;
          #pragma unroll
          for (int nt = 0; nt < 4; ++nt){
            const int b2 = nt*16 + row;
            short4_t hb = ld_bf4_cg(fh_l + (size_t)b2*D_ + cc);
            short4_t o;
            #pragma unroll
            for (int r = 0; r < 4; ++r) o[r] = f2bf((acc[nt][r] + pbv[r]) * bf2f(hb[r]));
            st_bf4_cg(P.hp1 + (size_t)b2*D_ + cc, o);
          }
        } else {
          const int cc = c0 - 2048;
          #pragma unroll
          for (int nt = 0; nt < 4; ++nt){
            const int b2 = nt*16 + row;
            float4_t vv;
            #pragma unroll
            for (int r = 0; r < 4; ++r) vv[r] = acc[nt][r] + pbv[r];
            st_f4_cg(P.polp + (size_t)b2*12288 + cc, vv);
          }
        }
      }
      gsync(P.bar, ++ph * NBLK);

      // ============ S3: f-gates (two K=1024 GEMMs) + f-cell ============
      if (blk < 64){
        const int nt3 = wq;
        const int j0 = blk*16;
        const short* wIr[4]; const short* wHr[4];
        #pragma unroll
        for (int g = 0; g < 4; ++g){
          wIr[g] = fwi + (size_t)(g*D_ + j0 + row)*D_ + quad*8;
          wHr[g] = fwh + (size_t)(g*D_ + j0 + row)*D_ + quad*8;
        }
        const short* bx = P.xp0 + (size_t)(nt3*16 + row)*D_ + quad*8;
        const short* bh = P.hp1 + (size_t)(nt3*16 + row)*D_ + quad*8;
        float4_t aI[4] = {{0.f,0.f,0.f,0.f},{0.f,0.f,0.f,0.f},{0.f,0.f,0.f,0.f},{0.f,0.f,0.f,0.f}};
        float4_t aH[4] = {{0.f,0.f,0.f,0.f},{0.f,0.f,0.f,0.f},{0.f,0.f,0.f,0.f},{0.f,0.f,0.f,0.f}};
        #pragma unroll 2
        for (int ks = 0; ks < 32; ++ks){
          const int kg = ks*32;
          short8 bxf = ld_bf8_cg(bx + kg);
          short8 bhf = ld_bf8_cg(bh + kg);
          #pragma unroll
          for (int g = 0; g < 4; ++g){
            short8 ai  = *(const short8*)(wIr[g] + kg);
            short8 ah8 = *(const short8*)(wHr[g] + kg);
            aI[g] = __builtin_amdgcn_mfma_f32_16x16x32_bf16(ai,  bxf, aI[g], 0, 0, 0);
            aH[g] = __builtin_amdgcn_mfma_f32_16x16x32_bf16(ah8, bhf, aH[g], 0, 0, 0);
          }
        }
        const int b3 = nt3*16 + row;
        const int jr = j0 + quad*4;
        float4_t gl[4];
        #pragma unroll
        for (int g = 0; g < 4; ++g){
          const float* pbase = P.polp + (size_t)b3*12288 + g*D_ + jr;
          float4_t p2 = ld_f4_cg(pbase);
          float4_t p3 = ld_f4_cg(pbase + 4096);
          float4_t p4 = ld_f4_cg(pbase + 8192);
          float4_t fbv = *(const float4_t*)(fb + g*D_ + jr);
          #pragma unroll
          for (int r = 0; r < 4; ++r)
            gl[g][r] = aI[g][r]*p2[r] + fbv[r]*p4[r] + aH[g][r]*p3[r];
        }
        float4_t cold = *(const float4_t*)(fc_l + (size_t)b3*D_ + jr);   // block-private
        float4_t cnew, hnew;
        #pragma unroll
        for (int r = 0; r < 4; ++r){
          float c2 = sigf(gl[1][r])*cold[r] + sigf(gl[0][r])*tanhf_(gl[2][r]);
          float h2 = sigf(gl[3][r])*tanhf_(c2);
          cnew[r] = c2; hnew[r] = h2;
        }
        *(float4_t*)(fc_l + (size_t)b3*D_ + jr) = cnew;                  // block-private
        short4_t hb;
        #pragma unroll
        for (int r = 0; r < 4; ++r) hb[r] = f2bf(hnew[r]);
        st_bf4_cg(fh_l + (size_t)b3*D_ + jr, hb);
        if (l == 1)
          __builtin_nontemporal_store(hnew,
              (float4_t*)(P.out + (size_t)t*B_*D_ + (size_t)b3*D_ + jr));
      }
      gsync(P.bar, ++ph * NBLK);
    }
  }
}

extern "C" void kernel_launch(void* const* d_in, const int* in_sizes, int n_in,
                              void* d_out, int out_size, void* d_ws, size_t ws_size,
                              hipStream_t stream) {
  const float* x = (const float*)d_in[0];
  const float* a_wih[2] = {(const float*)d_in[1],  (const float*)d_in[10]};
  const float* a_whh[2] = {(const float*)d_in[2],  (const float*)d_in[11]};
  const float* a_bih[2] = {(const float*)d_in[3],  (const float*)d_in[12]};
  const float* a_bhh[2] = {(const float*)d_in[4],  (const float*)d_in[13]};
  const float* p_w[2]   = {(const float*)d_in[5],  (const float*)d_in[14]};
  const float* p_b[2]   = {(const float*)d_in[6],  (const float*)d_in[15]};
  const float* f_wih[2] = {(const float*)d_in[7],  (const float*)d_in[16]};
  const float* f_whh[2] = {(const float*)d_in[8],  (const float*)d_in[17]};
  const float* f_b[2]   = {(const float*)d_in[9],  (const float*)d_in[18]};

  char* w = (char*)d_ws;
  float* gates = (float*)(w + 0);          // 512*64*4        = 131072
  float* ac    = (float*)(w + 131072);     // [l][par][128*64]= 131072
  float* fc    = (float*)(w + 262144);     // [l][64*1024]    = 524288
  float* polp  = (float*)(w + 786432);     // 64*12288*4      = 3145728
  short* xp0   = (short*)(w + 3932160);    // 64*1024*2       = 131072
  short* hp1   = (short*)(w + 4063232);    // 131072
  short* fhbf  = (short*)(w + 4194304);    // [l][64*1024]    = 262144
  short* ahbf  = (short*)(w + 4456448);    // [l][par][64*128]= 65536
  short* Wcat  = (short*)(w + 4521984);    // [l][512*2304]   = 4718592
  short* pwbf  = (short*)(w + 9240576);    // [l][14336*128]  = 7340032
  short* fwihb = (short*)(w + 16580608);   // [l][4096*1024]  = 16777216
  short* fwhhb = (short*)(w + 33357824);   // 16777216 -> end 50135040
  unsigned* bar = (unsigned*)(w + 50135040); // 64 B barrier counter

  // zero recurrent state: ac+fc, fh_bf+ah_bf, barrier counter
  hipMemsetAsync(w + 131072, 0, 655360, stream);
  hipMemsetAsync(w + 4194304, 0, 327680, stream);
  hipMemsetAsync(w + 50135040, 0, 64, stream);

  // weight conversion
  for (int l = 0; l < 2; ++l){
    pk_cat<<<dim3(9,512), 256, 0, stream>>>(a_wih[l], a_whh[l], Wcat + (size_t)l*512*KCAT_);
    pk_conv<<<(PSZ_*A_ + 255)/256, 256, 0, stream>>>(p_w[l], pwbf + (size_t)l*PSZ_*A_, PSZ_*A_);
    pk_conv<<<(4*D_*D_ + 255)/256, 256, 0, stream>>>(f_wih[l], fwihb + (size_t)l*4*D_*D_, 4*D_*D_);
    pk_conv<<<(4*D_*D_ + 255)/256, 256, 0, stream>>>(f_whh[l], fwhhb + (size_t)l*4*D_*D_, 4*D_*D_);
  }

  Args A;
  A.x = x;
  A.Wcat0 = Wcat;  A.Wcat1 = Wcat + (size_t)512*KCAT_;
  A.bih0 = a_bih[0]; A.bih1 = a_bih[1];
  A.bhh0 = a_bhh[0]; A.bhh1 = a_bhh[1];
  A.pw0 = pwbf;    A.pw1 = pwbf + (size_t)PSZ_*A_;
  A.pb0 = p_b[0];  A.pb1 = p_b[1];
  A.fwi0 = fwihb;  A.fwi1 = fwihb + (size_t)4*D_*D_;
  A.fwh0 = fwhhb;  A.fwh1 = fwhhb + (size_t)4*D_*D_;
  A.fb0 = f_b[0];  A.fb1 = f_b[1];
  A.gates = gates; A.ac = ac; A.fc = fc; A.polp = polp;
  A.xp0 = xp0; A.hp1 = hp1; A.fhbf = fhbf; A.ahbf = ahbf;
  A.out = (float*)d_out;
  A.bar = bar;

  fused<<<NBLK, 256, 0, stream>>>(A);
}

// Round 3
// 81753.540 us; speedup vs baseline: 1.6773x; 1.1831x over previous
//
#include <hip/hip_runtime.h>

#define T_ 512
#define B_ 64
#define D_ 1024
#define A_ 128
#define KCAT_ 2304   // 2176 (wih) + 128 (whh)
#define PSZ_ 14336
#define NBLK 256
#define RS_ 1032     // LDS weight row stride (shorts): 16B-aligned, 2-way-conflict-free

typedef __attribute__((ext_vector_type(8))) short short8;
typedef __attribute__((ext_vector_type(4))) short short4_t;
typedef __attribute__((ext_vector_type(4))) float float4_t;
typedef __attribute__((ext_vector_type(2))) unsigned long long ull2;

__device__ __forceinline__ float sigf(float x){ return 1.0f/(1.0f + __expf(-x)); }
__device__ __forceinline__ float tanhf_(float x){ return 2.0f/(1.0f + __expf(-2.0f*x)) - 1.0f; }

__device__ __forceinline__ short f2bf(float f){
  unsigned u = __builtin_bit_cast(unsigned, f);
  u += 0x7fffu + ((u >> 16) & 1u);           // RNE
  return (short)(u >> 16);
}
__device__ __forceinline__ float bf2f(short s){
  unsigned u = ((unsigned)(unsigned short)s) << 16;
  return __builtin_bit_cast(float, u);
}

// ---- coherent (agent-scope, LLC-backed, no cache-maintenance) accessors ----
__device__ __forceinline__ unsigned ld_u32_cg(const void* p){
  return __hip_atomic_load((const unsigned*)p, __ATOMIC_RELAXED, __HIP_MEMORY_SCOPE_AGENT);
}
__device__ __forceinline__ unsigned long long ld_u64_cg(const void* p){
  return __hip_atomic_load((const unsigned long long*)p, __ATOMIC_RELAXED, __HIP_MEMORY_SCOPE_AGENT);
}
__device__ __forceinline__ void st_u32_cg(void* p, unsigned v){
  __hip_atomic_store((unsigned*)p, v, __ATOMIC_RELAXED, __HIP_MEMORY_SCOPE_AGENT);
}
__device__ __forceinline__ void st_u64_cg(void* p, unsigned long long v){
  __hip_atomic_store((unsigned long long*)p, v, __ATOMIC_RELAXED, __HIP_MEMORY_SCOPE_AGENT);
}
__device__ __forceinline__ float ld_f_cg(const float* p){
  unsigned u = ld_u32_cg(p); return __builtin_bit_cast(float, u);
}
__device__ __forceinline__ void st_f_cg(float* p, float v){
  st_u32_cg(p, __builtin_bit_cast(unsigned, v));
}
__device__ __forceinline__ short8 ld_bf8_cg(const short* p){
  ull2 t; t.x = ld_u64_cg(p); t.y = ld_u64_cg(p + 4);
  return __builtin_bit_cast(short8, t);
}
__device__ __forceinline__ short4_t ld_bf4_cg(const short* p){
  return __builtin_bit_cast(short4_t, ld_u64_cg(p));
}
__device__ __forceinline__ float4_t ld_f4_cg(const float* p){
  ull2 t; t.x = ld_u64_cg(p); t.y = ld_u64_cg(p + 2);
  return __builtin_bit_cast(float4_t, t);
}
__device__ __forceinline__ void st_bf4_cg(short* p, short4_t v){
  st_u64_cg(p, __builtin_bit_cast(unsigned long long, v));
}
__device__ __forceinline__ void st_f4_cg(float* p, float4_t v){
  ull2 t = __builtin_bit_cast(ull2, v);
  st_u64_cg(p, t.x); st_u64_cg(p + 2, t.y);
}

// ---------- prep kernels (once per launch) ----------
__global__ __launch_bounds__(256) void pk_cat(const float* __restrict__ wih,
                                              const float* __restrict__ whh,
                                              short* __restrict__ dst){
  int c = blockIdx.x*256 + threadIdx.x;     // 0..2303
  int n = blockIdx.y;                       // 0..511
  if (c >= KCAT_) return;
  float v = (c < 2176) ? wih[(size_t)n*2176 + c] : whh[n*A_ + (c - 2176)];
  dst[(size_t)n*KCAT_ + c] = f2bf(v);
}
__global__ __launch_bounds__(256) void pk_conv(const float* __restrict__ src,
                                               short* __restrict__ dst, int n){
  int i = blockIdx.x*256 + threadIdx.x;
  if (i < n) dst[i] = f2bf(src[i]);
}

// ---------- persistent fused kernel ----------
struct Args {
  const float* x;
  const short* Wcat0; const short* Wcat1;
  const float* bih0;  const float* bih1;
  const float* bhh0;  const float* bhh1;
  const short* pw0;   const short* pw1;
  const float* pb0;   const float* pb1;
  const float* fwi32_0; const float* fwi32_1;   // fp32 f_wih (converted in prologue)
  const float* fwh32_0; const float* fwh32_1;   // fp32 f_whh
  const float* fb0;   const float* fb1;
  float* gates; float* ac; float* fc; float* polp;
  short* xp0; short* hp1; short* fhbf; short* ahbf;
  float* out;
  unsigned* flags;    // [NBLK] phase flags, 64B-spaced (no atomic contention)
};

__global__ __launch_bounds__(256, 1) void fused(Args P){
  const int tid  = threadIdx.x;
  const int blk  = blockIdx.x;
  const int wq   = tid >> 6;
  const int lane = tid & 63;
  const int row  = lane & 15, quad = lane >> 4;

  // LDS: pinned S3 weight slice (this block's 8 j-rows x 4 gates, I and H)
  __shared__ short wlds[2][32][RS_];   // 132,096 B
  __shared__ short ah_s[64*136];       //  17,408 B  -> total 149.5 KB

  // ---- prologue: convert this block's fwih/fwhh slice fp32 -> bf16 LDS ----
  {
    const int l3 = blk >> 7, jt = blk & 127;
    const float* srcI = l3 ? P.fwi32_1 : P.fwi32_0;
    const float* srcH = l3 ? P.fwh32_1 : P.fwh32_0;
    for (int e = tid; e < 8192; e += 256){     // 32 rows x 256 float4
      const int rr = e >> 8;                   // packed row = g*8 + r
      const int k4 = (e & 255) << 2;
      const int g = rr >> 3, r = rr & 7;
      const size_t off = ((size_t)(g*1024 + jt*8 + r))*1024 + k4;
      float4_t vI = *(const float4_t*)(srcI + off);
      float4_t vH = *(const float4_t*)(srcH + off);
      short4_t oI, oH;
      #pragma unroll
      for (int j = 0; j < 4; ++j){ oI[j] = f2bf(vI[j]); oH[j] = f2bf(vH[j]); }
      *(short4_t*)&wlds[0][rr][k4] = oI;
      *(short4_t*)&wlds[1][rr][k4] = oH;
    }
    __syncthreads();
  }

  unsigned ph = 0;

  for (int t = 0; t < T_; ++t){
    const int par = t & 1, cur = par ^ 1;
    const float* xt = P.x + (size_t)t*B_*D_;
    #pragma unroll
    for (int l = 0; l < 2; ++l){
      const short* Wcat = l ? P.Wcat1 : P.Wcat0;
      const float* bih  = l ? P.bih1  : P.bih0;
      const float* bhh  = l ? P.bhh1  : P.bhh0;
      const short* pw   = l ? P.pw1   : P.pw0;
      const float* pb   = l ? P.pb1   : P.pb0;
      const float* fb   = l ? P.fb1   : P.fb0;
      short* fh_l = P.fhbf + (size_t)l*B_*D_;
      const short* ahp = l ? (P.ahbf + (0*2 + cur)*B_*A_)   // ah[0] this step
                           : (P.ahbf + (1*2 + par)*B_*A_);  // ah[1] prev step
      const short* ahs = P.ahbf + (l*2 + par)*B_*A_;
      short* ah_out    = P.ahbf + (l*2 + cur)*B_*A_;
      const float* ac_old = P.ac + (l*2 + par)*A_*B_;
      float* ac_new       = P.ac + (l*2 + cur)*A_*B_;
      float* fc_l = P.fc + (size_t)l*B_*D_;

      // ===== S1: a-gates GEMM [512x64, K=2304] — 32 blocks, full-K per wave =====
      if (blk < 32){
        const int m0 = blk*16;
        const int bq = wq*16 + row;
        const short* wrow = Wcat + (size_t)(m0 + row)*KCAT_ + quad*8;
        float4_t acc = {0.f,0.f,0.f,0.f};
        if (l == 0){
          const float* xp = xt + (size_t)bq*D_ + quad*8;
          #pragma unroll 4
          for (int ks = 0; ks < 32; ++ks){
            short8 a = *(const short8*)(wrow + ks*32);
            float4_t x0 = *(const float4_t*)(xp + ks*32);
            float4_t x1 = *(const float4_t*)(xp + ks*32 + 4);
            short8 bfr;
            #pragma unroll
            for (int r = 0; r < 4; ++r){ bfr[r] = f2bf(x0[r]); bfr[4+r] = f2bf(x1[r]); }
            acc = __builtin_amdgcn_mfma_f32_16x16x32_bf16(a, bfr, acc, 0, 0, 0);
          }
        } else {
          const short* xp = P.fhbf + (size_t)bq*D_ + quad*8;  // layer0 fh (this step)
          #pragma unroll 4
          for (int ks = 0; ks < 32; ++ks){
            short8 a = *(const short8*)(wrow + ks*32);
            short8 bfr = ld_bf8_cg(xp + ks*32);
            acc = __builtin_amdgcn_mfma_f32_16x16x32_bf16(a, bfr, acc, 0, 0, 0);
          }
        }
        {
          const short* hp = fh_l + (size_t)bq*D_ + quad*8;
          #pragma unroll 4
          for (int ks = 0; ks < 32; ++ks){
            short8 a = *(const short8*)(wrow + 1024 + ks*32);
            short8 bfr = ld_bf8_cg(hp + ks*32);
            acc = __builtin_amdgcn_mfma_f32_16x16x32_bf16(a, bfr, acc, 0, 0, 0);
          }
        }
        #pragma unroll
        for (int ks = 0; ks < 4; ++ks){
          short8 a = *(const short8*)(wrow + 2048 + ks*32);
          short8 bfr = ld_bf8_cg(ahp + bq*A_ + quad*8 + ks*32);
          acc = __builtin_amdgcn_mfma_f32_16x16x32_bf16(a, bfr, acc, 0, 0, 0);
        }
        #pragma unroll
        for (int ks = 0; ks < 4; ++ks){
          short8 a = *(const short8*)(wrow + 2176 + ks*32);
          short8 bfr = ld_bf8_cg(ahs + bq*A_ + quad*8 + ks*32);
          acc = __builtin_amdgcn_mfma_f32_16x16x32_bf16(a, bfr, acc, 0, 0, 0);
        }
        #pragma unroll
        for (int r = 0; r < 4; ++r){
          const int n = m0 + quad*4 + r;
          st_f_cg(&P.gates[n*B_ + bq], acc[r] + bih[n] + bhh[n]);
        }
      }
      // ---- barrier 1 (contention-free flag barrier) ----
      {
        ++ph;
        __syncthreads();
        if (tid == 0) st_u32_cg(P.flags + blk*16, ph);
        for (;;){
          int bad = (ld_u32_cg(P.flags + tid*16) < ph);
          if (__syncthreads_count(bad) == 0) break;
          __builtin_amdgcn_s_sleep(1);
        }
      }

      // ===== S2: a-cell (redundant per block) + pol GEMM — 224 blocks =====
      if (blk < 224){
        const int b = tid & 63, q = tid >> 6;
        unsigned long long pk = 0;
        #pragma unroll 8
        for (int jj = 0; jj < 32; ++jj){
          const int j = q*32 + jj;
          float gi = ld_f_cg(&P.gates[(j      )*B_ + b]);
          float gf = ld_f_cg(&P.gates[(j + 128)*B_ + b]);
          float gg = ld_f_cg(&P.gates[(j + 256)*B_ + b]);
          float go = ld_f_cg(&P.gates[(j + 384)*B_ + b]);
          float c  = ld_f_cg(&ac_old[j*B_ + b]);
          float c2 = sigf(gf)*c + sigf(gi)*tanhf_(gg);
          float h2 = sigf(go)*tanhf_(c2);
          short hb = f2bf(h2);
          ah_s[b*136 + j] = hb;
          if (blk == 0){
            st_f_cg(&ac_new[j*B_ + b], c2);
            pk |= (unsigned long long)(unsigned short)hb << ((jj & 3)*16);
            if ((jj & 3) == 3){ st_u64_cg(ah_out + b*A_ + (j - 3), pk); pk = 0; }
          }
        }
        __syncthreads();
        const int m0 = (blk*4 + wq)*16;
        const short* wrow = pw + (size_t)(m0 + row)*A_ + quad*8;
        float4_t acc[4] = {{0.f,0.f,0.f,0.f},{0.f,0.f,0.f,0.f},{0.f,0.f,0.f,0.f},{0.f,0.f,0.f,0.f}};
        #pragma unroll
        for (int ks = 0; ks < 4; ++ks){
          short8 a = *(const short8*)(wrow + ks*32);
          #pragma unroll
          for (int nt = 0; nt < 4; ++nt){
            short8 bf8 = *(const short8*)&ah_s[(nt*16 + row)*136 + ks*32 + quad*8];
            acc[nt] = __builtin_amdgcn_mfma_f32_16x16x32_bf16(a, bf8, acc[nt], 0, 0, 0);
          }
        }
        const int c0 = m0 + quad*4;
        float4_t pbv = *(const float4_t*)(pb + c0);
        if (m0 < 1024){
          #pragma unroll
          for (int nt = 0; nt < 4; ++nt){
            const int b2 = nt*16 + row;
            float4_t xv;
            if (l == 0){ xv = *(const float4_t*)(xt + (size_t)b2*D_ + c0); }
            else {
              short4_t xb = ld_bf4_cg(P.fhbf + (size_t)b2*D_ + c0);
              #pragma unroll
              for (int r = 0; r < 4; ++r) xv[r] = bf2f(xb[r]);
            }
            short4_t o;
            #pragma unroll
            for (int r = 0; r < 4; ++r) o[r] = f2bf((acc[nt][r] + pbv[r]) * xv[r]);
            st_bf4_cg(P.xp0 + (size_t)b2*D_ + c0, o);
          }
        } else if (m0 < 2048){
          const int cc = c0 - 1024;
          #pragma unroll
          for (int nt = 0; nt < 4; ++nt){
            const int b2 = nt*16 + row;
            short4_t hb = ld_bf4_cg(fh_l + (size_t)b2*D_ + cc);
            short4_t o;
            #pragma unroll
            for (int r = 0; r < 4; ++r) o[r] = f2bf((acc[nt][r] + pbv[r]) * bf2f(hb[r]));
            st_bf4_cg(P.hp1 + (size_t)b2*D_ + cc, o);
          }
        } else {
          const int cc = c0 - 2048;
          #pragma unroll
          for (int nt = 0; nt < 4; ++nt){
            const int b2 = nt*16 + row;
            float4_t vv;
            #pragma unroll
            for (int r = 0; r < 4; ++r) vv[r] = acc[nt][r] + pbv[r];
            st_f4_cg(P.polp + (size_t)b2*12288 + cc, vv);
          }
        }
      }
      // ---- barrier 2 ----
      {
        ++ph;
        __syncthreads();
        if (tid == 0) st_u32_cg(P.flags + blk*16, ph);
        for (;;){
          int bad = (ld_u32_cg(P.flags + tid*16) < ph);
          if (__syncthreads_count(bad) == 0) break;
          __builtin_amdgcn_s_sleep(1);
        }
      }

      // ===== S3: f-gates from LDS-pinned weights + f-cell — 128 blocks (this l) =====
      if ((blk >> 7) == l){
        const int jt = blk & 127;
        const int b  = wq*16 + row;
        const short* bx = P.xp0 + (size_t)b*D_ + quad*8;
        const short* bh = P.hp1 + (size_t)b*D_ + quad*8;
        float4_t aI[2] = {{0.f,0.f,0.f,0.f},{0.f,0.f,0.f,0.f}};
        float4_t aH[2] = {{0.f,0.f,0.f,0.f},{0.f,0.f,0.f,0.f}};
        #pragma unroll 2
        for (int ks = 0; ks < 32; ++ks){
          short8 bxf = ld_bf8_cg(bx + ks*32);
          short8 bhf = ld_bf8_cg(bh + ks*32);
          #pragma unroll
          for (int tp = 0; tp < 2; ++tp){
            short8 aIf = *(const short8*)&wlds[0][tp*16 + row][quad*8 + ks*32];
            short8 aHf = *(const short8*)&wlds[1][tp*16 + row][quad*8 + ks*32];
            aI[tp] = __builtin_amdgcn_mfma_f32_16x16x32_bf16(aIf, bxf, aI[tp], 0, 0, 0);
            aH[tp] = __builtin_amdgcn_mfma_f32_16x16x32_bf16(aHf, bhf, aH[tp], 0, 0, 0);
          }
        }
        // slot (tp, r): D-row m = quad*4+r -> gate g = tp*2 + (m>>3), jlocal = m&7
        const int g0 = quad >> 1;            // 0: quads 0,1 (gates 0,2) ; 1: quads 2,3 (1,3)
        const int jb = (quad & 1) * 4;
        const int jg = jt*8 + jb;            // global j (0..1023), 4 contiguous
        float gl[2][4];
        #pragma unroll
        for (int tp = 0; tp < 2; ++tp){
          const int g = tp*2 + g0;
          const float* pbase = P.polp + (size_t)b*12288 + g*1024 + jg;
          float4_t p2 = ld_f4_cg(pbase);
          float4_t p3 = ld_f4_cg(pbase + 4096);
          float4_t p4 = ld_f4_cg(pbase + 8192);
          float4_t fbv = *(const float4_t*)(fb + g*1024 + jg);
          #pragma unroll
          for (int r = 0; r < 4; ++r)
            gl[tp][r] = aI[tp][r]*p2[r] + aH[tp][r]*p3[r] + fbv[r]*p4[r];
        }
        // exchange with partner quad (lane^32): quads 0,1 hold {i,g}; 2,3 hold {f,o}
        float glx[2][4];
        #pragma unroll
        for (int tp = 0; tp < 2; ++tp)
          #pragma unroll
          for (int r = 0; r < 4; ++r)
            glx[tp][r] = __shfl_xor(gl[tp][r], 32, 64);
        if (quad < 2){
          float4_t cold = *(const float4_t*)(fc_l + (size_t)b*D_ + jg);   // block-private
          float4_t cnew, hnew;
          #pragma unroll
          for (int r = 0; r < 4; ++r){
            float c2 = sigf(glx[0][r])*cold[r] + sigf(gl[0][r])*tanhf_(gl[1][r]);
            float h2 = sigf(glx[1][r])*tanhf_(c2);
            cnew[r] = c2; hnew[r] = h2;
          }
          *(float4_t*)(fc_l + (size_t)b*D_ + jg) = cnew;                  // block-private
          short4_t hb;
          #pragma unroll
          for (int r = 0; r < 4; ++r) hb[r] = f2bf(hnew[r]);
          st_bf4_cg(fh_l + (size_t)b*D_ + jg, hb);
          if (l == 1)
            __builtin_nontemporal_store(hnew,
                (float4_t*)(P.out + (size_t)t*B_*D_ + (size_t)b*D_ + jg));
        }
      }
      // ---- barrier 3 ----
      {
        ++ph;
        __syncthreads();
        if (tid == 0) st_u32_cg(P.flags + blk*16, ph);
        for (;;){
          int bad = (ld_u32_cg(P.flags + tid*16) < ph);
          if (__syncthreads_count(bad) == 0) break;
          __builtin_amdgcn_s_sleep(1);
        }
      }
    }
  }
}

extern "C" void kernel_launch(void* const* d_in, const int* in_sizes, int n_in,
                              void* d_out, int out_size, void* d_ws, size_t ws_size,
                              hipStream_t stream) {
  const float* x = (const float*)d_in[0];
  const float* a_wih[2] = {(const float*)d_in[1],  (const float*)d_in[10]};
  const float* a_whh[2] = {(const float*)d_in[2],  (const float*)d_in[11]};
  const float* a_bih[2] = {(const float*)d_in[3],  (const float*)d_in[12]};
  const float* a_bhh[2] = {(const float*)d_in[4],  (const float*)d_in[13]};
  const float* p_w[2]   = {(const float*)d_in[5],  (const float*)d_in[14]};
  const float* p_b[2]   = {(const float*)d_in[6],  (const float*)d_in[15]};
  const float* f_wih[2] = {(const float*)d_in[7],  (const float*)d_in[16]};
  const float* f_whh[2] = {(const float*)d_in[8],  (const float*)d_in[17]};
  const float* f_b[2]   = {(const float*)d_in[9],  (const float*)d_in[18]};

  char* w = (char*)d_ws;
  float* gates = (float*)(w + 0);          // 512*64*4        = 131072
  float* ac    = (float*)(w + 131072);     // [l][par][128*64]= 131072
  float* fc    = (float*)(w + 262144);     // [l][64*1024]    = 524288
  float* polp  = (float*)(w + 786432);     // 64*12288*4      = 3145728
  short* xp0   = (short*)(w + 3932160);    // 64*1024*2       = 131072
  short* hp1   = (short*)(w + 4063232);    // 131072
  short* fhbf  = (short*)(w + 4194304);    // [l][64*1024]    = 262144
  short* ahbf  = (short*)(w + 4456448);    // [l][par][64*128]= 65536
  short* Wcat  = (short*)(w + 4521984);    // [l][512*2304]   = 4718592
  short* pwbf  = (short*)(w + 9240576);    // [l][14336*128]  = 7340032
  unsigned* flags = (unsigned*)(w + 16580608); // 256*64B      = 16384 -> end 16596992

  // zero recurrent state: ac+fc, fh_bf+ah_bf, barrier flags
  hipMemsetAsync(w + 131072, 0, 655360, stream);
  hipMemsetAsync(w + 4194304, 0, 327680, stream);
  hipMemsetAsync(w + 16580608, 0, 16384, stream);

  // weight conversion (only the small L2-resident ones; fwih/fwhh go to LDS in-kernel)
  for (int l = 0; l < 2; ++l){
    pk_cat<<<dim3(9,512), 256, 0, stream>>>(a_wih[l], a_whh[l], Wcat + (size_t)l*512*KCAT_);
    pk_conv<<<(PSZ_*A_ + 255)/256, 256, 0, stream>>>(p_w[l], pwbf + (size_t)l*PSZ_*A_, PSZ_*A_);
  }

  Args A;
  A.x = x;
  A.Wcat0 = Wcat;  A.Wcat1 = Wcat + (size_t)512*KCAT_;
  A.bih0 = a_bih[0]; A.bih1 = a_bih[1];
  A.bhh0 = a_bhh[0]; A.bhh1 = a_bhh[1];
  A.pw0 = pwbf;    A.pw1 = pwbf + (size_t)PSZ_*A_;
  A.pb0 = p_b[0];  A.pb1 = p_b[1];
  A.fwi32_0 = f_wih[0]; A.fwi32_1 = f_wih[1];
  A.fwh32_0 = f_whh[0]; A.fwh32_1 = f_whh[1];
  A.fb0 = f_b[0];  A.fb1 = f_b[1];
  A.gates = gates; A.ac = ac; A.fc = fc; A.polp = polp;
  A.xp0 = xp0; A.hp1 = hp1; A.fhbf = fhbf; A.ahbf = ahbf;
  A.out = (float*)d_out;
  A.flags = flags;

  fused<<<NBLK, 256, 0, stream>>>(A);
}